// Round 1
// baseline (449.862 us; speedup 1.0000x reference)
//
#include <hip/hip_runtime.h>
#include <cmath>
#include <complex>

namespace {

constexpr int TLEN   = 65536;
constexpr int NCH    = 512;          // 32*16 channels
constexpr int LEXT   = TLEN + 54;    // 65590: 27-sample odd extension each side
constexpr int CHUNK  = 1024;
constexpr int NCHUNK = 65;           // ceil(65590/1024)
constexpr int WARM   = 765;          // decay e^{-0.0425*765} ~ 8e-15
constexpr int ROWS4  = 16408;        // padded row-groups (s4); valid s4 <= 16398
constexpr size_t BUF_FLOATS = (size_t)ROWS4 * 2048;  // rows4 * 512ch * 4t

// Layout: value at "storage row" s (s = e+5 for ext/y, e = extended-time index)
// lives at float offset (s>>2)*2048 + ch*4 + (s&3).  I.e. float4 groups of 4
// consecutive time samples per channel, channels contiguous -> coalesced
// dwordx4 loads with lane = channel.

struct Coefs {
  float b0,b1,b2,b3,b4,b5,b6,b7,b8;
  float na1,na2,na3,na4,na5,na6,na7,na8;   // -a[1..8]
  float zi0,zi1,zi2,zi3,zi4,zi5,zi6,zi7;
};

// one DF2T step; coefficients are SGPR-uniform kernel args
#define IIR_STEP(xv, yv)                                  \
  do {                                                    \
    yv = fmaf(cf.b0, (xv), z0);                           \
    z0 = fmaf(cf.na1, yv, fmaf(cf.b1, (xv), z1));         \
    z1 = fmaf(cf.na2, yv, fmaf(cf.b2, (xv), z2));         \
    z2 = fmaf(cf.na3, yv, fmaf(cf.b3, (xv), z3));         \
    z3 = fmaf(cf.na4, yv, fmaf(cf.b4, (xv), z4));         \
    z4 = fmaf(cf.na5, yv, fmaf(cf.b5, (xv), z5));         \
    z5 = fmaf(cf.na6, yv, fmaf(cf.b6, (xv), z6));         \
    z6 = fmaf(cf.na7, yv, fmaf(cf.b7, (xv), z7));         \
    z7 = fmaf(cf.na8, yv, cf.b8 * (xv));                  \
  } while (0)

// ---------------- K1: interior transpose x[ch][t] -> ext rows s=t+32 ----------
__global__ __launch_bounds__(256) void k_transpose(const float* __restrict__ x,
                                                   float* __restrict__ ext) {
  __shared__ float lds[64][65];   // +1 pad: conflict-free both phases
  const int bt = blockIdx.x;      // 0..1023  (t tile)
  const int bm = blockIdx.y;      // 0..7     (ch tile)
  const int tid = threadIdx.x;
  const int t0 = bt * 64, m0 = bm * 64;
  {
    const int tl = tid & 63;
    const int r0 = tid >> 6;
#pragma unroll
    for (int i = 0; i < 16; ++i) {
      int ml = r0 + i * 4;
      lds[ml][tl] = x[(size_t)(m0 + ml) * TLEN + (t0 + tl)];
    }
  }
  __syncthreads();
  {
    const int ml = tid & 63;
    const int k0 = tid >> 6;
#pragma unroll
    for (int i = 0; i < 4; ++i) {
      int k = k0 + i * 4;                 // 0..15
      int s4 = bt * 16 + 8 + k;           // storage row-group; s = 64*bt+32+4k+q
      float4 v = make_float4(lds[ml][4 * k + 0], lds[ml][4 * k + 1],
                             lds[ml][4 * k + 2], lds[ml][4 * k + 3]);
      *reinterpret_cast<float4*>(ext + (size_t)s4 * 2048 + (size_t)(m0 + ml) * 4) = v;
    }
  }
}

// ---------------- K1e: odd-extension edges (54 rows x 512 ch) -----------------
__global__ void k_edges(const float* __restrict__ x, float* __restrict__ ext) {
  const int r = blockIdx.x;   // 0..53
  const int m = threadIdx.x;  // 0..511
  int e, src;
  float base;
  if (r < 27) {               // left: ext[e]=2*x[0]-x[27-e], e=r
    e = r; src = 27 - r;
    base = x[(size_t)m * TLEN];
  } else {                    // right: ext[27+T+j]=2*x[T-1]-x[T-2-j]
    int j = r - 27;
    e = TLEN + 27 + j; src = TLEN - 2 - j;
    base = x[(size_t)m * TLEN + (TLEN - 1)];
  }
  float v = 2.0f * base - x[(size_t)m * TLEN + src];
  int s = e + 5;
  ext[(size_t)(s >> 2) * 2048 + (size_t)m * 4 + (s & 3)] = v;
}

// ---------------- K2: forward chunked scan ext -> y ---------------------------
__global__ __launch_bounds__(256) void k_fwd(const float* __restrict__ ext,
                                             float* __restrict__ yb, Coefs cf) {
  const int m = blockIdx.y * 256 + threadIdx.x;  // channel
  const int c = blockIdx.x;                      // chunk
  const int cs = c * CHUNK;
  float z0, z1, z2, z3, z4, z5, z6, z7;
  {
    int e0 = (c == 0) ? 0 : (cs - WARM);
    int s0 = e0 + 5;
    float x0 = ext[(size_t)(s0 >> 2) * 2048 + (size_t)m * 4 + (s0 & 3)];
    z0 = cf.zi0 * x0; z1 = cf.zi1 * x0; z2 = cf.zi2 * x0; z3 = cf.zi3 * x0;
    z4 = cf.zi4 * x0; z5 = cf.zi5 * x0; z6 = cf.zi6 * x0; z7 = cf.zi7 * x0;
  }
  const float4* xv4 = reinterpret_cast<const float4*>(ext);
  float4* yv4 = reinterpret_cast<float4*>(yb);
  int s4_begin, store_s4;
  if (c == 0) {
    // scalar head e=0..2 (rows 5..7), exact zi init
#pragma unroll
    for (int s = 5; s < 8; ++s) {
      float xin = ext[(size_t)(s >> 2) * 2048 + (size_t)m * 4 + (s & 3)];
      float yv; IIR_STEP(xin, yv);
      yb[(size_t)(s >> 2) * 2048 + (size_t)m * 4 + (s & 3)] = yv;
    }
    s4_begin = 2; store_s4 = 2;
  } else {
    s4_begin = (cs - WARM + 5) >> 2;   // aligned: cs-760 divisible by 4
    store_s4 = 256 * c + 1;            // first stored e = cs-1
  }
  const int s4_last = (c == NCHUNK - 1) ? ((LEXT + 4) >> 2) : (256 * (c + 1));
  // software pipeline: 4 row-groups (16 samples) in flight
  float4 b0 = xv4[(size_t)(s4_begin + 0) * 512 + m];
  float4 b1 = xv4[(size_t)(s4_begin + 1) * 512 + m];
  float4 b2 = xv4[(size_t)(s4_begin + 2) * 512 + m];
  float4 b3 = xv4[(size_t)(s4_begin + 3) * 512 + m];
  for (int g = s4_begin; g <= s4_last; g += 4) {
    float4 c0 = b0, c1 = b1, c2 = b2, c3 = b3;
    b0 = xv4[(size_t)(g + 4) * 512 + m];   // prefetch (padded rows: safe)
    b1 = xv4[(size_t)(g + 5) * 512 + m];
    b2 = xv4[(size_t)(g + 6) * 512 + m];
    b3 = xv4[(size_t)(g + 7) * 512 + m];
#pragma unroll
    for (int j = 0; j < 4; ++j) {
      float4 xq = (j == 0) ? c0 : (j == 1) ? c1 : (j == 2) ? c2 : c3;
      const int sg = g + j;
      float4 o;
      IIR_STEP(xq.x, o.x);
      IIR_STEP(xq.y, o.y);
      IIR_STEP(xq.z, o.z);
      IIR_STEP(xq.w, o.w);
      if (sg >= store_s4 && sg <= s4_last)
        yv4[(size_t)sg * 512 + m] = o;
    }
  }
}

// ---------------- K3: backward chunked scan y -> decimated out ----------------
__global__ __launch_bounds__(256) void k_bwd(const float* __restrict__ yb,
                                             float* __restrict__ out, Coefs cf) {
  const int m = blockIdx.y * 256 + threadIdx.x;
  const int c = blockIdx.x;
  const int us = c * CHUNK;
  const int ue = min(us + CHUNK, LEXT);
  float z0, z1, z2, z3, z4, z5, z6, z7;
  const int u0 = (c == 0) ? 0 : (us - WARM);
  {
    int sI = 65594 - u0;                 // reversed: u -> row s = 65594-u
    float y0 = yb[(size_t)(sI >> 2) * 2048 + (size_t)m * 4 + (sI & 3)];
    z0 = cf.zi0 * y0; z1 = cf.zi1 * y0; z2 = cf.zi2 * y0; z3 = cf.zi3 * y0;
    z4 = cf.zi4 * y0; z5 = cf.zi5 * y0; z6 = cf.zi6 * y0; z7 = cf.zi7 * y0;
  }
  const float4* yv4 = reinterpret_cast<const float4*>(yb);
  int s4_begin;
  if (c == 0) {
    // scalar head u=0..2 (rows 65594..65592); no valid outputs there
#pragma unroll
    for (int u = 0; u < 3; ++u) {
      int s = 65594 - u;
      float xin = yb[(size_t)(s >> 2) * 2048 + (size_t)m * 4 + (s & 3)];
      float wv; IIR_STEP(xin, wv);
      (void)wv;
    }
    s4_begin = 16397;
  } else {
    s4_begin = (65594 - u0 - 3) >> 2;    // row at u0 is q=3 of this group
  }
  const int s4_stop = (65595 - ue) >> 2;
  auto ld = [&](int r) {
    int rr = r < 0 ? 0 : r;
    return yv4[(size_t)rr * 512 + m];
  };
  float4 b0 = ld(s4_begin), b1 = ld(s4_begin - 1), b2 = ld(s4_begin - 2), b3 = ld(s4_begin - 3);
  for (int g = s4_begin; g >= s4_stop; g -= 4) {
    float4 c0 = b0, c1 = b1, c2 = b2, c3 = b3;
    b0 = ld(g - 4); b1 = ld(g - 5); b2 = ld(g - 6); b3 = ld(g - 7);
#pragma unroll
    for (int j = 0; j < 4; ++j) {
      const int sg = g - j;
      float4 q = (j == 0) ? c0 : (j == 1) ? c1 : (j == 2) ? c2 : c3;
      float w3, w2, w1, w0;
      IIR_STEP(q.w, w3);   // u ascending: q=3,2,1,0
      IIR_STEP(q.z, w2);
      IIR_STEP(q.y, w1);
      IIR_STEP(q.x, w0);
      (void)w3; (void)w2; (void)w1;
      const int u_out = 65594 - 4 * sg;  // q=0 sample; only u%4==2 yields output
      const int n = sg - 8;              // out[..,n] = w_rev[27+4n]
      if (u_out >= us && u_out < ue && n >= 0 && n < 16384)
        out[(size_t)m * 16384 + n] = w0;
    }
  }
}

// ---------------- host: exact cheby1/zi design in double ----------------------
static void solve8(double Mm[8][9], double* zi) {
  for (int col = 0; col < 8; ++col) {
    int piv = col;
    for (int r = col + 1; r < 8; ++r)
      if (std::fabs(Mm[r][col]) > std::fabs(Mm[piv][col])) piv = r;
    if (piv != col)
      for (int j = 0; j < 9; ++j) { double t = Mm[col][j]; Mm[col][j] = Mm[piv][j]; Mm[piv][j] = t; }
    double d = Mm[col][col];
    for (int j = col; j < 9; ++j) Mm[col][j] /= d;
    for (int r = 0; r < 8; ++r)
      if (r != col) {
        double f = Mm[r][col];
        if (f != 0.0)
          for (int j = col; j < 9; ++j) Mm[r][j] -= f * Mm[col][j];
      }
  }
  for (int i = 0; i < 8; ++i) zi[i] = Mm[i][8];
}

static Coefs make_coefs() {
  using cd = std::complex<double>;
  const int N = 8;
  const double rp = 0.05, Wn = 0.8 / 4.0;
  double eps = std::sqrt(std::pow(10.0, 0.1 * rp) - 1.0);
  double mu = std::asinh(1.0 / eps) / N;
  cd p[8];
  for (int i = 0; i < N; ++i) {
    double th = M_PI * (2.0 * (i + 1) - 1.0) / (2.0 * N);
    p[i] = cd(-std::sinh(mu) * std::sin(th), std::cosh(mu) * std::cos(th));
  }
  cd pr(1.0, 0.0);
  for (int i = 0; i < N; ++i) pr *= -p[i];
  double g = pr.real();
  g /= std::sqrt(1.0 + eps * eps);                 // N even
  const double fs = 2.0;
  double warped = 2.0 * fs * std::tan(M_PI * Wn / fs);
  for (int i = 0; i < N; ++i) p[i] *= warped;
  g *= std::pow(warped, (double)N);
  const double fs2 = 2.0 * fs;
  cd pd[8], dpr(1.0, 0.0);
  for (int i = 0; i < N; ++i) {
    pd[i] = (cd(fs2, 0.0) + p[i]) / (cd(fs2, 0.0) - p[i]);
    dpr *= (cd(fs2, 0.0) - p[i]);
  }
  double gd = g * (cd(1.0, 0.0) / dpr).real();
  static const double binom[9] = {1, 8, 28, 56, 70, 56, 28, 8, 1};
  double b[9], a[9];
  for (int i = 0; i < 9; ++i) b[i] = gd * binom[i];
  cd cp[9]; cp[0] = cd(1, 0);
  for (int i = 1; i < 9; ++i) cp[i] = cd(0, 0);
  for (int i = 0; i < N; ++i)
    for (int j = i + 1; j >= 1; --j) cp[j] -= pd[i] * cp[j - 1];
  for (int i = 0; i < 9; ++i) a[i] = cp[i].real();
  // zi = solve(I - companion(a)^T, b[1:]-a[1:]*b[0])
  double Mm[8][9];
  for (int i = 0; i < 8; ++i) {
    for (int j = 0; j < 9; ++j) Mm[i][j] = 0.0;
    Mm[i][0] += a[i + 1];
    Mm[i][i] += 1.0;
    if (i < 7) Mm[i][i + 1] = -1.0;
    Mm[i][8] = b[i + 1] - a[i + 1] * b[0];
  }
  double zi[8];
  solve8(Mm, zi);
  Coefs cf;
  cf.b0 = (float)b[0]; cf.b1 = (float)b[1]; cf.b2 = (float)b[2]; cf.b3 = (float)b[3];
  cf.b4 = (float)b[4]; cf.b5 = (float)b[5]; cf.b6 = (float)b[6]; cf.b7 = (float)b[7];
  cf.b8 = (float)b[8];
  cf.na1 = (float)(-a[1]); cf.na2 = (float)(-a[2]); cf.na3 = (float)(-a[3]);
  cf.na4 = (float)(-a[4]); cf.na5 = (float)(-a[5]); cf.na6 = (float)(-a[6]);
  cf.na7 = (float)(-a[7]); cf.na8 = (float)(-a[8]);
  cf.zi0 = (float)zi[0]; cf.zi1 = (float)zi[1]; cf.zi2 = (float)zi[2]; cf.zi3 = (float)zi[3];
  cf.zi4 = (float)zi[4]; cf.zi5 = (float)zi[5]; cf.zi6 = (float)zi[6]; cf.zi7 = (float)zi[7];
  return cf;
}

}  // namespace

extern "C" void kernel_launch(void* const* d_in, const int* in_sizes, int n_in,
                              void* d_out, int out_size, void* d_ws, size_t ws_size,
                              hipStream_t stream) {
  (void)in_sizes; (void)n_in; (void)out_size; (void)ws_size;
  const float* x = (const float*)d_in[0];
  float* out = (float*)d_out;
  float* ext = (float*)d_ws;                 // 134.4 MB
  float* yb  = ext + BUF_FLOATS;             // 134.4 MB
  Coefs cf = make_coefs();                   // pure host math, capture-safe
  hipLaunchKernelGGL(k_transpose, dim3(TLEN / 64, NCH / 64), dim3(256), 0, stream, x, ext);
  hipLaunchKernelGGL(k_edges, dim3(54), dim3(512), 0, stream, x, ext);
  hipLaunchKernelGGL(k_fwd, dim3(NCHUNK, 2), dim3(256), 0, stream, ext, yb, cf);
  hipLaunchKernelGGL(k_bwd, dim3(NCHUNK, 2), dim3(256), 0, stream, yb, out, cf);
}

// Round 2
// 341.571 us; speedup vs baseline: 1.3170x; 1.3170x over previous
//
#include <hip/hip_runtime.h>
#include <cmath>
#include <complex>

namespace {

constexpr int TLEN   = 65536;
constexpr int NCH    = 512;            // 32*16 channels
constexpr int LEXT   = TLEN + 54;      // 65590: 27-sample odd extension each side
constexpr int CHUNK  = 256;
constexpr int NCHUNK = 257;            // ceil(65590/256)
constexpr int PAD    = 4;              // storage row s = e + PAD
constexpr int ROWS4  = 16408;          // valid groups <= 16398, + prefetch slack
constexpr size_t BUF_FLOATS = (size_t)ROWS4 * 2048;

// Layout: extended-time sample e lives at storage row s = e+4, float offset
// (s>>2)*2048 + ch*4 + (s&3): float4 groups of 4 consecutive time samples per
// channel, channels contiguous -> lane=channel gives coalesced dwordx4.

struct Coefs {
  float b0,b1,b2,b3,b4,b5,b6,b7,b8;
  float na1,na2,na3,na4,na5,na6,na7,na8;   // -a[1..8]
  float zi0,zi1,zi2,zi3,zi4,zi5,zi6,zi7;
};

#define IIR_STEP(xv, yv)                                  \
  do {                                                    \
    yv = fmaf(cf.b0, (xv), z0);                           \
    z0 = fmaf(cf.na1, yv, fmaf(cf.b1, (xv), z1));         \
    z1 = fmaf(cf.na2, yv, fmaf(cf.b2, (xv), z2));         \
    z2 = fmaf(cf.na3, yv, fmaf(cf.b3, (xv), z3));         \
    z3 = fmaf(cf.na4, yv, fmaf(cf.b4, (xv), z4));         \
    z4 = fmaf(cf.na5, yv, fmaf(cf.b5, (xv), z5));         \
    z5 = fmaf(cf.na6, yv, fmaf(cf.b6, (xv), z6));         \
    z6 = fmaf(cf.na7, yv, fmaf(cf.b7, (xv), z7));         \
    z7 = fmaf(cf.na8, yv, cf.b8 * (xv));                  \
  } while (0)

// ---------------- K1: interior transpose x[ch][t] -> ext (s = t+31) ----------
__global__ __launch_bounds__(256) void k_transpose(const float* __restrict__ x,
                                                   float* __restrict__ ext) {
  __shared__ float lds[64][65];
  const int bt = blockIdx.x;      // 0..1023  (t tile of 64)
  const int bm = blockIdx.y;      // 0..7     (ch tile of 64)
  const int tid = threadIdx.x;
  const int t0 = bt * 64, m0 = bm * 64;
  {
    const int tl4 = (tid & 15) * 4;
    const int ch0 = tid >> 4;
#pragma unroll
    for (int i = 0; i < 4; ++i) {
      int ch = ch0 + i * 16;
      float4 v = *reinterpret_cast<const float4*>(x + (size_t)(m0 + ch) * TLEN + t0 + tl4);
      lds[ch][tl4 + 0] = v.x; lds[ch][tl4 + 1] = v.y;
      lds[ch][tl4 + 2] = v.z; lds[ch][tl4 + 3] = v.w;
    }
  }
  __syncthreads();
  {
    const int ch = tid & 63;
    const int kk = tid >> 6;    // 0..3
    const int gm = m0 + ch;
#pragma unroll
    for (int i = 0; i < 4; ++i) {
      int gl = 8 + kk + i * 4;              // 8..23
      int g = 16 * bt + gl;
      if (gl <= 22) {                       // full group: t = 4*gl-31 .. 4*gl-28
        int tl = 4 * gl - 31;
        float4 v = make_float4(lds[ch][tl], lds[ch][tl + 1], lds[ch][tl + 2], lds[ch][tl + 3]);
        *reinterpret_cast<float4*>(ext + (size_t)g * 2048 + (size_t)gm * 4) = v;
      } else {                              // gl==23: q=0,1,2 from t=61,62,63
        float* base = ext + (size_t)g * 2048 + (size_t)gm * 4;
        base[0] = lds[ch][61]; base[1] = lds[ch][62]; base[2] = lds[ch][63];
        // and group 16bt+7 q=3 from t=0
        ext[(size_t)(16 * bt + 7) * 2048 + (size_t)gm * 4 + 3] = lds[ch][0];
      }
    }
  }
}

// ---------------- K1e: odd-extension edges (54 rows x 512 ch) -----------------
__global__ void k_edges(const float* __restrict__ x, float* __restrict__ ext) {
  const int r = blockIdx.x;   // 0..53
  const int m = threadIdx.x;  // 0..511
  int e, src;
  float base;
  if (r < 27) {               // left: ext[e]=2*x[0]-x[27-e], e=0..26
    e = r; src = 27 - r;
    base = x[(size_t)m * TLEN];
  } else {                    // right: ext[65563+j]=2*x[T-1]-x[T-2-j]
    int j = r - 27;
    e = TLEN + 27 + j; src = TLEN - 2 - j;
    base = x[(size_t)m * TLEN + (TLEN - 1)];
  }
  float v = 2.0f * base - x[(size_t)m * TLEN + src];
  int s = e + PAD;
  ext[(size_t)(s >> 2) * 2048 + (size_t)m * 4 + (s & 3)] = v;
}

// ---------------- K2: forward chunked scan ext -> y ---------------------------
// chunk c owns e in [256c, min(256c+255, 65589)]; warm-up from e=256(c-1).
// All starts/stores are group-aligned (PAD=4): no scalar heads.
__global__ __launch_bounds__(256) void k_fwd(const float* __restrict__ ext,
                                             float* __restrict__ yb, Coefs cf) {
  const int m = blockIdx.y * 256 + threadIdx.x;
  const int c = blockIdx.x;                      // 0..256
  float z0, z1, z2, z3, z4, z5, z6, z7;
  const int e0 = (c == 0) ? 0 : 256 * (c - 1);
  const int s4_begin = (e0 + PAD) >> 2;          // c==0: 1, else 64(c-1)+1
  {
    float x0 = ext[(size_t)s4_begin * 2048 + (size_t)m * 4];   // q=0
    z0 = cf.zi0 * x0; z1 = cf.zi1 * x0; z2 = cf.zi2 * x0; z3 = cf.zi3 * x0;
    z4 = cf.zi4 * x0; z5 = cf.zi5 * x0; z6 = cf.zi6 * x0; z7 = cf.zi7 * x0;
  }
  const int store_s4 = 64 * c + 1;
  const int s4_last = min(64 * c + 64, 16398);
  const float4* xv = reinterpret_cast<const float4*>(ext);
  float4* yv = reinterpret_cast<float4*>(yb);
  float4 b0 = xv[(size_t)(s4_begin + 0) * 512 + m];
  float4 b1 = xv[(size_t)(s4_begin + 1) * 512 + m];
  float4 b2 = xv[(size_t)(s4_begin + 2) * 512 + m];
  float4 b3 = xv[(size_t)(s4_begin + 3) * 512 + m];
  for (int g = s4_begin; g <= s4_last; g += 4) {
    float4 c0 = b0, c1 = b1, c2 = b2, c3 = b3;
    b0 = xv[(size_t)(g + 4) * 512 + m];          // padded rows: safe overrun
    b1 = xv[(size_t)(g + 5) * 512 + m];
    b2 = xv[(size_t)(g + 6) * 512 + m];
    b3 = xv[(size_t)(g + 7) * 512 + m];
#pragma unroll
    for (int j = 0; j < 4; ++j) {
      float4 xq = (j == 0) ? c0 : (j == 1) ? c1 : (j == 2) ? c2 : c3;
      const int sg = g + j;
      float4 o;
      IIR_STEP(xq.x, o.x);
      IIR_STEP(xq.y, o.y);
      IIR_STEP(xq.z, o.z);
      IIR_STEP(xq.w, o.w);
      if (sg >= store_s4 && sg <= s4_last)
        yv[(size_t)sg * 512 + m] = o;
    }
  }
}

// ---------------- K3: backward chunked scan y -> decimated (staged transposed)
// reversed axis u = 0..65589, w[u] = y[65589-u] at row s = 65593-u.
// chunk c owns u in [256c, uend]; warm from u = 256c-258 (c>=2; aligned q=3).
// output n = g-7 comes from q=3 of group g (u = 65590-4g, u%4==2).
__global__ __launch_bounds__(256) void k_bwd(const float* __restrict__ yb,
                                             float* __restrict__ ot, Coefs cf) {
  const int m = blockIdx.y * 256 + threadIdx.x;
  const int c = blockIdx.x;
  const int uend = min(256 * (c + 1), LEXT) - 1;
  const int own_lo = 256 * c;
  float z0, z1, z2, z3, z4, z5, z6, z7;
  const int ustart = (c <= 1) ? 0 : (256 * c - 258);
  {
    int sI = 65593 - ustart;
    float y0 = yb[(size_t)(sI >> 2) * 2048 + (size_t)m * 4 + (sI & 3)];
    z0 = cf.zi0 * y0; z1 = cf.zi1 * y0; z2 = cf.zi2 * y0; z3 = cf.zi3 * y0;
    z4 = cf.zi4 * y0; z5 = cf.zi5 * y0; z6 = cf.zi6 * y0; z7 = cf.zi7 * y0;
  }
  int g_begin;
  if (c <= 1) {
    // scalar head u=0 (s=65593,q=1), u=1 (s=65592,q=0); both in group 16398
#pragma unroll
    for (int s = 65593; s >= 65592; --s) {
      float yin = yb[(size_t)(s >> 2) * 2048 + (size_t)m * 4 + (s & 3)];
      float wv; IIR_STEP(yin, wv);
      (void)wv;
    }
    g_begin = 16397;
  } else {
    g_begin = (65593 - ustart) >> 2;   // q=3 aligned
  }
  const int g_stop = (c <= 255) ? (16334 - 64 * c) : 1;
  const float4* yv = reinterpret_cast<const float4*>(yb);
  auto ld = [&](int r) {
    int rr = r < 0 ? 0 : r;
    return yv[(size_t)rr * 512 + m];
  };
  float4 b0 = ld(g_begin), b1 = ld(g_begin - 1), b2 = ld(g_begin - 2), b3 = ld(g_begin - 3);
  for (int g = g_begin; g >= g_stop; g -= 4) {
    float4 c0 = b0, c1 = b1, c2 = b2, c3 = b3;
    b0 = ld(g - 4); b1 = ld(g - 5); b2 = ld(g - 6); b3 = ld(g - 7);
#pragma unroll
    for (int j = 0; j < 4; ++j) {
      const int sg = g - j;
      float4 q = (j == 0) ? c0 : (j == 1) ? c1 : (j == 2) ? c2 : c3;
      float w3, w2, w1, w0;
      IIR_STEP(q.w, w3);   // ascending u: q=3,2,1,0
      IIR_STEP(q.z, w2);
      IIR_STEP(q.y, w1);
      IIR_STEP(q.x, w0);
      (void)w2; (void)w1; (void)w0;
      const int u3 = 65590 - 4 * sg;   // q=3 sample; u3 % 4 == 2
      const int n = sg - 7;
      if (u3 >= own_lo && u3 <= uend && n >= 0 && n < 16384)
        ot[(size_t)n * 512 + m] = w3;  // coalesced: lane = m
    }
  }
}

// ---------------- K4: transpose staging ot[n][m] -> out[m][n] -----------------
__global__ __launch_bounds__(256) void k_outT(const float* __restrict__ ot,
                                              float* __restrict__ out) {
  __shared__ float lds[64][65];
  const int bn = blockIdx.x;     // 0..255  (n tile of 64)
  const int bm = blockIdx.y;     // 0..7    (m tile of 64)
  const int tid = threadIdx.x;
  const int n0 = bn * 64, m0 = bm * 64;
  {
    const int ml4 = (tid & 15) * 4;
    const int nl0 = tid >> 4;
#pragma unroll
    for (int i = 0; i < 4; ++i) {
      int nl = nl0 + i * 16;
      float4 v = *reinterpret_cast<const float4*>(ot + (size_t)(n0 + nl) * 512 + m0 + ml4);
      lds[ml4 + 0][nl] = v.x; lds[ml4 + 1][nl] = v.y;
      lds[ml4 + 2][nl] = v.z; lds[ml4 + 3][nl] = v.w;
    }
  }
  __syncthreads();
  {
    const int nl4 = (tid & 15) * 4;
    const int ml0 = tid >> 4;
#pragma unroll
    for (int i = 0; i < 4; ++i) {
      int ml = ml0 + i * 16;
      float4 v = make_float4(lds[ml][nl4], lds[ml][nl4 + 1], lds[ml][nl4 + 2], lds[ml][nl4 + 3]);
      *reinterpret_cast<float4*>(out + (size_t)(m0 + ml) * 16384 + n0 + nl4) = v;
    }
  }
}

// ---------------- host: exact cheby1/zi design in double ----------------------
static void solve8(double Mm[8][9], double* zi) {
  for (int col = 0; col < 8; ++col) {
    int piv = col;
    for (int r = col + 1; r < 8; ++r)
      if (std::fabs(Mm[r][col]) > std::fabs(Mm[piv][col])) piv = r;
    if (piv != col)
      for (int j = 0; j < 9; ++j) { double t = Mm[col][j]; Mm[col][j] = Mm[piv][j]; Mm[piv][j] = t; }
    double d = Mm[col][col];
    for (int j = col; j < 9; ++j) Mm[col][j] /= d;
    for (int r = 0; r < 8; ++r)
      if (r != col) {
        double f = Mm[r][col];
        if (f != 0.0)
          for (int j = col; j < 9; ++j) Mm[r][j] -= f * Mm[col][j];
      }
  }
  for (int i = 0; i < 8; ++i) zi[i] = Mm[i][8];
}

static Coefs make_coefs() {
  using cd = std::complex<double>;
  const int N = 8;
  const double rp = 0.05, Wn = 0.8 / 4.0;
  double eps = std::sqrt(std::pow(10.0, 0.1 * rp) - 1.0);
  double mu = std::asinh(1.0 / eps) / N;
  cd p[8];
  for (int i = 0; i < N; ++i) {
    double th = M_PI * (2.0 * (i + 1) - 1.0) / (2.0 * N);
    p[i] = cd(-std::sinh(mu) * std::sin(th), std::cosh(mu) * std::cos(th));
  }
  cd pr(1.0, 0.0);
  for (int i = 0; i < N; ++i) pr *= -p[i];
  double g = pr.real();
  g /= std::sqrt(1.0 + eps * eps);                 // N even
  const double fs = 2.0;
  double warped = 2.0 * fs * std::tan(M_PI * Wn / fs);
  for (int i = 0; i < N; ++i) p[i] *= warped;
  g *= std::pow(warped, (double)N);
  const double fs2 = 2.0 * fs;
  cd pd[8], dpr(1.0, 0.0);
  for (int i = 0; i < N; ++i) {
    pd[i] = (cd(fs2, 0.0) + p[i]) / (cd(fs2, 0.0) - p[i]);
    dpr *= (cd(fs2, 0.0) - p[i]);
  }
  double gd = g * (cd(1.0, 0.0) / dpr).real();
  static const double binom[9] = {1, 8, 28, 56, 70, 56, 28, 8, 1};
  double b[9], a[9];
  for (int i = 0; i < 9; ++i) b[i] = gd * binom[i];
  cd cp[9]; cp[0] = cd(1, 0);
  for (int i = 1; i < 9; ++i) cp[i] = cd(0, 0);
  for (int i = 0; i < N; ++i)
    for (int j = i + 1; j >= 1; --j) cp[j] -= pd[i] * cp[j - 1];
  for (int i = 0; i < 9; ++i) a[i] = cp[i].real();
  double Mm[8][9];
  for (int i = 0; i < 8; ++i) {
    for (int j = 0; j < 9; ++j) Mm[i][j] = 0.0;
    Mm[i][0] += a[i + 1];
    Mm[i][i] += 1.0;
    if (i < 7) Mm[i][i + 1] = -1.0;
    Mm[i][8] = b[i + 1] - a[i + 1] * b[0];
  }
  double zi[8];
  solve8(Mm, zi);
  Coefs cf;
  cf.b0 = (float)b[0]; cf.b1 = (float)b[1]; cf.b2 = (float)b[2]; cf.b3 = (float)b[3];
  cf.b4 = (float)b[4]; cf.b5 = (float)b[5]; cf.b6 = (float)b[6]; cf.b7 = (float)b[7];
  cf.b8 = (float)b[8];
  cf.na1 = (float)(-a[1]); cf.na2 = (float)(-a[2]); cf.na3 = (float)(-a[3]);
  cf.na4 = (float)(-a[4]); cf.na5 = (float)(-a[5]); cf.na6 = (float)(-a[6]);
  cf.na7 = (float)(-a[7]); cf.na8 = (float)(-a[8]);
  cf.zi0 = (float)zi[0]; cf.zi1 = (float)zi[1]; cf.zi2 = (float)zi[2]; cf.zi3 = (float)zi[3];
  cf.zi4 = (float)zi[4]; cf.zi5 = (float)zi[5]; cf.zi6 = (float)zi[6]; cf.zi7 = (float)zi[7];
  return cf;
}

}  // namespace

extern "C" void kernel_launch(void* const* d_in, const int* in_sizes, int n_in,
                              void* d_out, int out_size, void* d_ws, size_t ws_size,
                              hipStream_t stream) {
  (void)in_sizes; (void)n_in; (void)out_size; (void)ws_size;
  const float* x = (const float*)d_in[0];
  float* out = (float*)d_out;
  float* ext = (float*)d_ws;                 // 134.4 MB
  float* yb  = ext + BUF_FLOATS;             // 134.4 MB
  float* ot  = ext;                          // reuse ext after k_fwd (33.6 MB)
  Coefs cf = make_coefs();                   // pure host math, capture-safe
  hipLaunchKernelGGL(k_transpose, dim3(TLEN / 64, NCH / 64), dim3(256), 0, stream, x, ext);
  hipLaunchKernelGGL(k_edges, dim3(54), dim3(512), 0, stream, x, ext);
  hipLaunchKernelGGL(k_fwd, dim3(NCHUNK, 2), dim3(256), 0, stream, ext, yb, cf);
  hipLaunchKernelGGL(k_bwd, dim3(NCHUNK, 2), dim3(256), 0, stream, yb, ot, cf);
  hipLaunchKernelGGL(k_outT, dim3(16384 / 64, NCH / 64), dim3(256), 0, stream, ot, out);
}

// Round 3
// 335.182 us; speedup vs baseline: 1.3421x; 1.0191x over previous
//
#include <hip/hip_runtime.h>
#include <cmath>
#include <complex>

namespace {

constexpr int TLEN   = 65536;
constexpr int NCH    = 512;            // 32*16 channels
constexpr int LEXT   = TLEN + 54;      // 65590: 27-sample odd extension each side
constexpr int NCHUNK = 257;            // ceil(65590/256), chunk = 256 samples
constexpr int PAD    = 5;              // storage row s = e + 5  (=> s = t + 32)
constexpr int ROWS4  = 16416;          // valid groups <= 16398, + prefetch slack
constexpr size_t BUF_FLOATS = (size_t)ROWS4 * 2048;

// Layout: extended-time sample e lives at storage row s = e+5, float offset
// (s>>2)*2048 + ch*4 + (s&3): float4 groups of 4 consecutive time samples per
// channel, channels contiguous -> lane=channel gives coalesced 1KB dwordx4.

struct Coefs {
  float b0,b1,b2,b3,b4,b5,b6,b7,b8;
  float na1,na2,na3,na4,na5,na6,na7,na8;   // -a[1..8]
  float zi0,zi1,zi2,zi3,zi4,zi5,zi6,zi7;
};

#define IIR_STEP(xv, yv)                                  \
  do {                                                    \
    yv = fmaf(cf.b0, (xv), z0);                           \
    z0 = fmaf(cf.na1, yv, fmaf(cf.b1, (xv), z1));         \
    z1 = fmaf(cf.na2, yv, fmaf(cf.b2, (xv), z2));         \
    z2 = fmaf(cf.na3, yv, fmaf(cf.b3, (xv), z3));         \
    z3 = fmaf(cf.na4, yv, fmaf(cf.b4, (xv), z4));         \
    z4 = fmaf(cf.na5, yv, fmaf(cf.b5, (xv), z5));         \
    z5 = fmaf(cf.na6, yv, fmaf(cf.b6, (xv), z6));         \
    z6 = fmaf(cf.na7, yv, fmaf(cf.b7, (xv), z7));         \
    z7 = fmaf(cf.na8, yv, cf.b8 * (xv));                  \
  } while (0)

// ---------------- K1: transpose x[ch][t] -> ext (s = t+32; 64ch x 256t tiles)
// PAD=5 => every block emits exactly 64 full, aligned storage groups.
__global__ __launch_bounds__(256) void k_transpose(const float* __restrict__ x,
                                                   float* __restrict__ ext) {
  __shared__ float lds[64 * 260];          // pitch 260: bank-perfect, 16B-aligned rows
  const int bx = blockIdx.x;               // 0..255   t0 = 256*bx
  const int m0 = blockIdx.y * 64;          // 0..7 -> ch tile
  const int tid = threadIdx.x;
  const int t0 = bx * 256;
#pragma unroll
  for (int i = 0; i < 16; ++i) {
    int idx = tid + i * 256;
    int ch = idx >> 6;                     // wave-uniform
    int tq = idx & 63;                     // lane -> contiguous 1KB row read
    float4 v = *reinterpret_cast<const float4*>(
        x + (size_t)(m0 + ch) * TLEN + t0 + tq * 4);
    *reinterpret_cast<float4*>(&lds[ch * 260 + tq * 4]) = v;
  }
  __syncthreads();
#pragma unroll
  for (int i = 0; i < 16; ++i) {
    int idx = tid + i * 256;
    int j = idx >> 6;                      // wave-uniform group 0..63
    int ch = idx & 63;                     // lane -> contiguous 1KB group write
    float4 v = *reinterpret_cast<const float4*>(&lds[ch * 260 + j * 4]);
    *reinterpret_cast<float4*>(
        ext + (size_t)(64 * bx + 8 + j) * 2048 + (size_t)(m0 + ch) * 4) = v;
  }
}

// ---------------- K1e: odd-extension edges (54 rows x 512 ch) -----------------
__global__ void k_edges(const float* __restrict__ x, float* __restrict__ ext) {
  const int r = blockIdx.x;   // 0..53
  const int m = threadIdx.x;  // 0..511
  int e, src;
  float base;
  if (r < 27) {               // left: ext[e]=2*x[0]-x[27-e], e=0..26
    e = r; src = 27 - r;
    base = x[(size_t)m * TLEN];
  } else {                    // right: ext[65563+j]=2*x[T-1]-x[T-2-j]
    int j = r - 27;
    e = TLEN + 27 + j; src = TLEN - 2 - j;
    base = x[(size_t)m * TLEN + (TLEN - 1)];
  }
  float v = 2.0f * base - x[(size_t)m * TLEN + src];
  int s = e + PAD;
  ext[(size_t)(s >> 2) * 2048 + (size_t)m * 4 + (s & 3)] = v;
}

// ---------------- K2: forward chunked scan ext -> y ---------------------------
// chunk c owns e in [256c, 256c+255]; warm-up 253 samples (group-aligned start).
// Stores groups [64c+1, 64c+64] (c>=1); c==0: scalar head e=0..2 + groups 2..64.
__global__ __launch_bounds__(256) void k_fwd(const float* __restrict__ ext,
                                             float* __restrict__ yb, Coefs cf) {
  const int m = blockIdx.y * 256 + threadIdx.x;
  const int c = blockIdx.x;                      // 0..256
  float z0, z1, z2, z3, z4, z5, z6, z7;
  int s4_begin, store_s4;
  if (c == 0) {
    float x0 = ext[(size_t)1 * 2048 + (size_t)m * 4 + 1];    // s=5 (e=0)
    z0 = cf.zi0 * x0; z1 = cf.zi1 * x0; z2 = cf.zi2 * x0; z3 = cf.zi3 * x0;
    z4 = cf.zi4 * x0; z5 = cf.zi5 * x0; z6 = cf.zi6 * x0; z7 = cf.zi7 * x0;
#pragma unroll
    for (int s = 5; s < 8; ++s) {                // e = 0,1,2
      float xin = ext[(size_t)(s >> 2) * 2048 + (size_t)m * 4 + (s & 3)];
      float yv; IIR_STEP(xin, yv);
      yb[(size_t)(s >> 2) * 2048 + (size_t)m * 4 + (s & 3)] = yv;
    }
    s4_begin = 2; store_s4 = 2;
  } else {
    s4_begin = 64 * c - 62;                      // e0 = 256c-253, q0-aligned
    float x0 = ext[(size_t)s4_begin * 2048 + (size_t)m * 4];
    z0 = cf.zi0 * x0; z1 = cf.zi1 * x0; z2 = cf.zi2 * x0; z3 = cf.zi3 * x0;
    z4 = cf.zi4 * x0; z5 = cf.zi5 * x0; z6 = cf.zi6 * x0; z7 = cf.zi7 * x0;
    store_s4 = 64 * c + 1;
  }
  const int s4_last = min(64 * c + 64, 16398);
  const float4* xv = reinterpret_cast<const float4*>(ext);
  float4* yv = reinterpret_cast<float4*>(yb);
  float4 b0 = xv[(size_t)(s4_begin + 0) * 512 + m];
  float4 b1 = xv[(size_t)(s4_begin + 1) * 512 + m];
  float4 b2 = xv[(size_t)(s4_begin + 2) * 512 + m];
  float4 b3 = xv[(size_t)(s4_begin + 3) * 512 + m];
  float4 b4 = xv[(size_t)(s4_begin + 4) * 512 + m];
  float4 b5 = xv[(size_t)(s4_begin + 5) * 512 + m];
  float4 b6 = xv[(size_t)(s4_begin + 6) * 512 + m];
  float4 b7 = xv[(size_t)(s4_begin + 7) * 512 + m];
  for (int g = s4_begin; g <= s4_last; g += 4) {
    float4 c0 = b0, c1 = b1, c2 = b2, c3 = b3;
    b0 = b4; b1 = b5; b2 = b6; b3 = b7;
    b4 = xv[(size_t)(g + 8) * 512 + m];          // padded rows: safe overrun
    b5 = xv[(size_t)(g + 9) * 512 + m];
    b6 = xv[(size_t)(g + 10) * 512 + m];
    b7 = xv[(size_t)(g + 11) * 512 + m];
#pragma unroll
    for (int j = 0; j < 4; ++j) {
      float4 xq = (j == 0) ? c0 : (j == 1) ? c1 : (j == 2) ? c2 : c3;
      const int sg = g + j;
      float4 o;
      IIR_STEP(xq.x, o.x);
      IIR_STEP(xq.y, o.y);
      IIR_STEP(xq.z, o.z);
      IIR_STEP(xq.w, o.w);
      if (sg >= store_s4 && sg <= s4_last)
        yv[(size_t)sg * 512 + m] = o;
    }
  }
}

// ---------------- K3: backward chunked scan y -> quad-packed decimated output
// reversed axis u: w[u] = y[65589-u] at row s = 65594-u.  chunk c owns
// u in [256c, 256c+255]; warm 261 from u=256c-261 (q3- and quad-aligned).
// Each outer iter (groups g..g-3) yields outputs n = g-11..g-8 -> one float4
// into ot2[(g-11)/4][m][4] (coalesced 1KB).
__global__ __launch_bounds__(256) void k_bwd(const float* __restrict__ yb,
                                             float* __restrict__ ot2, Coefs cf) {
  const int m = blockIdx.y * 256 + threadIdx.x;
  const int c = blockIdx.x;
  const int own_lo = 256 * c;
  float z0, z1, z2, z3, z4, z5, z6, z7;
  int g_begin;
  if (c <= 1) {
    float y0 = yb[(size_t)16398 * 2048 + (size_t)m * 4 + 2];   // s=65594 (u=0)
    z0 = cf.zi0 * y0; z1 = cf.zi1 * y0; z2 = cf.zi2 * y0; z3 = cf.zi3 * y0;
    z4 = cf.zi4 * y0; z5 = cf.zi5 * y0; z6 = cf.zi6 * y0; z7 = cf.zi7 * y0;
#pragma unroll
    for (int s = 65594; s >= 65584; --s) {       // u = 0..10 (no valid outputs)
      float yin = yb[(size_t)(s >> 2) * 2048 + (size_t)m * 4 + (s & 3)];
      float wv; IIR_STEP(yin, wv);
      (void)wv;
    }
    g_begin = 16395;
  } else {
    g_begin = 16463 - 64 * c;                    // u=256c-261 at q3 of g_begin
    float y0 = yb[(size_t)g_begin * 2048 + (size_t)m * 4 + 3];
    z0 = cf.zi0 * y0; z1 = cf.zi1 * y0; z2 = cf.zi2 * y0; z3 = cf.zi3 * y0;
    z4 = cf.zi4 * y0; z5 = cf.zi5 * y0; z6 = cf.zi6 * y0; z7 = cf.zi7 * y0;
  }
  const int g_stop = max(1, 16334 - 64 * c);
  const float4* yv = reinterpret_cast<const float4*>(yb);
  auto ld = [&](int r) {
    int rr = r < 0 ? 0 : r;
    return yv[(size_t)rr * 512 + m];
  };
  float4 b0 = ld(g_begin), b1 = ld(g_begin - 1), b2 = ld(g_begin - 2), b3 = ld(g_begin - 3);
  float4 b4 = ld(g_begin - 4), b5 = ld(g_begin - 5), b6 = ld(g_begin - 6), b7 = ld(g_begin - 7);
  for (int g = g_begin; g >= g_stop; g -= 4) {
    float4 c0 = b0, c1 = b1, c2 = b2, c3 = b3;
    b0 = b4; b1 = b5; b2 = b6; b3 = b7;
    b4 = ld(g - 8); b5 = ld(g - 9); b6 = ld(g - 10); b7 = ld(g - 11);
    float4 pack;
#pragma unroll
    for (int j = 0; j < 4; ++j) {
      float4 q = (j == 0) ? c0 : (j == 1) ? c1 : (j == 2) ? c2 : c3;
      float w3, w2, w1, w0;
      IIR_STEP(q.w, w3);   // ascending u within group: q3,q2,q1,q0
      IIR_STEP(q.z, w2);
      IIR_STEP(q.y, w1);
      IIR_STEP(q.x, w0);
      (void)w3; (void)w2; (void)w1;
      if (j == 0) pack.w = w0;          // n = g-8
      else if (j == 1) pack.z = w0;     // n = g-9
      else if (j == 2) pack.y = w0;     // n = g-10
      else pack.x = w0;                 // n = g-11
    }
    if (65594 - 4 * g >= own_lo && g >= 11 && g <= 16391)
      *reinterpret_cast<float4*>(ot2 + (size_t)((g - 11) >> 2) * 2048 + (size_t)m * 4) = pack;
  }
}

// ---------------- K4: quad-packed ot2[qn][m][4] -> out[m][16384] --------------
__global__ __launch_bounds__(256) void k_outT(const float* __restrict__ ot2,
                                              float* __restrict__ out) {
  __shared__ float4 lds4[64 * 65];      // pitch 65 float4s: bank-perfect
  const int q0 = blockIdx.x * 64;       // quad tile (4096 quads total)
  const int m0 = blockIdx.y * 64;
  const int tid = threadIdx.x;
#pragma unroll
  for (int i = 0; i < 16; ++i) {
    int idx = tid + i * 256;
    int ql = idx >> 6;                  // wave-uniform
    int ml = idx & 63;                  // lane -> 1KB contiguous read
    lds4[ql * 65 + ml] = *reinterpret_cast<const float4*>(
        ot2 + (size_t)(q0 + ql) * 2048 + (size_t)(m0 + ml) * 4);
  }
  __syncthreads();
#pragma unroll
  for (int i = 0; i < 16; ++i) {
    int idx = tid + i * 256;
    int ml = idx >> 6;                  // wave-uniform
    int ql = idx & 63;                  // lane -> 1KB contiguous write
    float4 v = lds4[ql * 65 + ml];
    *reinterpret_cast<float4*>(
        out + (size_t)(m0 + ml) * 16384 + (size_t)(q0 + ql) * 4) = v;
  }
}

// ---------------- host: exact cheby1/zi design in double ----------------------
static void solve8(double Mm[8][9], double* zi) {
  for (int col = 0; col < 8; ++col) {
    int piv = col;
    for (int r = col + 1; r < 8; ++r)
      if (std::fabs(Mm[r][col]) > std::fabs(Mm[piv][col])) piv = r;
    if (piv != col)
      for (int j = 0; j < 9; ++j) { double t = Mm[col][j]; Mm[col][j] = Mm[piv][j]; Mm[piv][j] = t; }
    double d = Mm[col][col];
    for (int j = col; j < 9; ++j) Mm[col][j] /= d;
    for (int r = 0; r < 8; ++r)
      if (r != col) {
        double f = Mm[r][col];
        if (f != 0.0)
          for (int j = col; j < 9; ++j) Mm[r][j] -= f * Mm[col][j];
      }
  }
  for (int i = 0; i < 8; ++i) zi[i] = Mm[i][8];
}

static Coefs make_coefs() {
  using cd = std::complex<double>;
  const int N = 8;
  const double rp = 0.05, Wn = 0.8 / 4.0;
  double eps = std::sqrt(std::pow(10.0, 0.1 * rp) - 1.0);
  double mu = std::asinh(1.0 / eps) / N;
  cd p[8];
  for (int i = 0; i < N; ++i) {
    double th = M_PI * (2.0 * (i + 1) - 1.0) / (2.0 * N);
    p[i] = cd(-std::sinh(mu) * std::sin(th), std::cosh(mu) * std::cos(th));
  }
  cd pr(1.0, 0.0);
  for (int i = 0; i < N; ++i) pr *= -p[i];
  double g = pr.real();
  g /= std::sqrt(1.0 + eps * eps);                 // N even
  const double fs = 2.0;
  double warped = 2.0 * fs * std::tan(M_PI * Wn / fs);
  for (int i = 0; i < N; ++i) p[i] *= warped;
  g *= std::pow(warped, (double)N);
  const double fs2 = 2.0 * fs;
  cd pd[8], dpr(1.0, 0.0);
  for (int i = 0; i < N; ++i) {
    pd[i] = (cd(fs2, 0.0) + p[i]) / (cd(fs2, 0.0) - p[i]);
    dpr *= (cd(fs2, 0.0) - p[i]);
  }
  double gd = g * (cd(1.0, 0.0) / dpr).real();
  static const double binom[9] = {1, 8, 28, 56, 70, 56, 28, 8, 1};
  double b[9], a[9];
  for (int i = 0; i < 9; ++i) b[i] = gd * binom[i];
  cd cp[9]; cp[0] = cd(1, 0);
  for (int i = 1; i < 9; ++i) cp[i] = cd(0, 0);
  for (int i = 0; i < N; ++i)
    for (int j = i + 1; j >= 1; --j) cp[j] -= pd[i] * cp[j - 1];
  for (int i = 0; i < 9; ++i) a[i] = cp[i].real();
  double Mm[8][9];
  for (int i = 0; i < 8; ++i) {
    for (int j = 0; j < 9; ++j) Mm[i][j] = 0.0;
    Mm[i][0] += a[i + 1];
    Mm[i][i] += 1.0;
    if (i < 7) Mm[i][i + 1] = -1.0;
    Mm[i][8] = b[i + 1] - a[i + 1] * b[0];
  }
  double zi[8];
  solve8(Mm, zi);
  Coefs cf;
  cf.b0 = (float)b[0]; cf.b1 = (float)b[1]; cf.b2 = (float)b[2]; cf.b3 = (float)b[3];
  cf.b4 = (float)b[4]; cf.b5 = (float)b[5]; cf.b6 = (float)b[6]; cf.b7 = (float)b[7];
  cf.b8 = (float)b[8];
  cf.na1 = (float)(-a[1]); cf.na2 = (float)(-a[2]); cf.na3 = (float)(-a[3]);
  cf.na4 = (float)(-a[4]); cf.na5 = (float)(-a[5]); cf.na6 = (float)(-a[6]);
  cf.na7 = (float)(-a[7]); cf.na8 = (float)(-a[8]);
  cf.zi0 = (float)zi[0]; cf.zi1 = (float)zi[1]; cf.zi2 = (float)zi[2]; cf.zi3 = (float)zi[3];
  cf.zi4 = (float)zi[4]; cf.zi5 = (float)zi[5]; cf.zi6 = (float)zi[6]; cf.zi7 = (float)zi[7];
  return cf;
}

}  // namespace

extern "C" void kernel_launch(void* const* d_in, const int* in_sizes, int n_in,
                              void* d_out, int out_size, void* d_ws, size_t ws_size,
                              hipStream_t stream) {
  (void)in_sizes; (void)n_in; (void)out_size; (void)ws_size;
  const float* x = (const float*)d_in[0];
  float* out = (float*)d_out;
  float* ext = (float*)d_ws;                 // 134.5 MB
  float* yb  = ext + BUF_FLOATS;             // 134.5 MB
  float* ot2 = ext;                          // reuse ext after k_fwd (33.6 MB)
  Coefs cf = make_coefs();                   // pure host math, capture-safe
  hipLaunchKernelGGL(k_transpose, dim3(TLEN / 256, NCH / 64), dim3(256), 0, stream, x, ext);
  hipLaunchKernelGGL(k_edges, dim3(54), dim3(512), 0, stream, x, ext);
  hipLaunchKernelGGL(k_fwd, dim3(NCHUNK, 2), dim3(256), 0, stream, ext, yb, cf);
  hipLaunchKernelGGL(k_bwd, dim3(NCHUNK, 2), dim3(256), 0, stream, yb, ot2, cf);
  hipLaunchKernelGGL(k_outT, dim3(4096 / 64, NCH / 64), dim3(256), 0, stream, ot2, out);
}

// Round 4
// 311.480 us; speedup vs baseline: 1.4443x; 1.0761x over previous
//
#include <hip/hip_runtime.h>
#include <cmath>
#include <complex>

namespace {

constexpr int TLEN   = 65536;
constexpr int NCH    = 512;            // 32*16 channels
constexpr int LEXT   = TLEN + 54;      // 65590 extended samples (e = 0..65589)
constexpr int PAD    = 5;              // storage row s = e + 5
constexpr size_t YB_ROWS = 16400;      // float4-groups in yb (valid g <= 16398)

// yb layout: sample e at row s=e+5, float offset (s>>2)*2048 + ch*4 + (s&3).
// 1KB-contiguous per (group, all 512 ch) -> lane=ch gives coalesced dwordx4.

struct Coefs {
  float b0,b1,b2,b3,b4,b5,b6,b7,b8;
  float na1,na2,na3,na4,na5,na6,na7,na8;   // -a[1..8]
  float zi0,zi1,zi2,zi3,zi4,zi5,zi6,zi7;
};

#define IIR_STEP(xv, yv)                                  \
  do {                                                    \
    yv = fmaf(cf.b0, (xv), z0);                           \
    z0 = fmaf(cf.na1, yv, fmaf(cf.b1, (xv), z1));         \
    z1 = fmaf(cf.na2, yv, fmaf(cf.b2, (xv), z2));         \
    z2 = fmaf(cf.na3, yv, fmaf(cf.b3, (xv), z3));         \
    z3 = fmaf(cf.na4, yv, fmaf(cf.b4, (xv), z4));         \
    z4 = fmaf(cf.na5, yv, fmaf(cf.b5, (xv), z5));         \
    z5 = fmaf(cf.na6, yv, fmaf(cf.b6, (xv), z6));         \
    z6 = fmaf(cf.na7, yv, fmaf(cf.b7, (xv), z7));         \
    z7 = fmaf(cf.na8, yv, cf.b8 * (xv));                  \
  } while (0)

// =============== K1: fused extension+transpose+forward scan ==================
// 512-sample chunks, warm-up 253.  chunk c (0..128) stores e in
// [512c-1, 512c+510] (c==0: [0,510]; c==128: [65535,65589]) as yb groups.
// LDS: 3-buffer ring of 64t x 64ch subtiles (pitch 65 -> all LDS 2-way free).
// All 4 waves load (issued 2 subtiles ahead, committed after scan); wave 0
// scans 64 steps per subtile from LDS.
template<int QOFF, bool VEC>
__device__ __forceinline__ void run_chunk(const float* __restrict__ x,
                                          float* __restrict__ yb,
                                          const Coefs& cf,
                                          float (&lds)[3][4160],
                                          int m0, int e0, int nsub,
                                          int store_lo, int store_hi) {
  const int tid  = threadIdx.x;
  const int lane = tid & 63;
  const int vtbase = e0 - 27;            // x-index of e0
  const int mIdx = m0 + lane;
  float4* yq = reinterpret_cast<float4*>(yb);
  const int tq  = tid & 15;              // VEC: float4-column within row
  const int chb = tid >> 4;              // VEC: base channel row (0..15)
  float4 rr0, rr1, rr2, rr3;             // VEC staging
  float rs[16];                          // edge staging

  auto issue = [&](int k) {
    const int vt0 = vtbase + 64 * k;
    if (VEC) {
      const float* p = x + (size_t)(m0 + chb) * TLEN + vt0 + 4 * tq;
      rr0 = *reinterpret_cast<const float4*>(p);
      rr1 = *reinterpret_cast<const float4*>(p + (size_t)16 * TLEN);
      rr2 = *reinterpret_cast<const float4*>(p + (size_t)32 * TLEN);
      rr3 = *reinterpret_cast<const float4*>(p + (size_t)48 * TLEN);
    } else {
#pragma unroll
      for (int i = 0; i < 16; ++i) {
        int idx = tid + 256 * i;
        int tl = idx & 63, ch = idx >> 6;
        int vt = vt0 + tl;
        const float* xr = x + (size_t)(m0 + ch) * TLEN;
        float v;
        if (vt < 0) v = 2.0f * xr[0] - xr[-vt];
        else if (vt >= TLEN) v = 2.0f * xr[TLEN - 1] - xr[2 * TLEN - 2 - vt];
        else v = xr[vt];
        rs[i] = v;
      }
    }
  };
  auto commit = [&](int k) {
    float* b = lds[k % 3];
    if (VEC) {
      const int base = 4 * tq * 65;
      b[base       + chb     ] = rr0.x; b[base + 65  + chb     ] = rr0.y;
      b[base + 130 + chb     ] = rr0.z; b[base + 195 + chb     ] = rr0.w;
      b[base       + chb + 16] = rr1.x; b[base + 65  + chb + 16] = rr1.y;
      b[base + 130 + chb + 16] = rr1.z; b[base + 195 + chb + 16] = rr1.w;
      b[base       + chb + 32] = rr2.x; b[base + 65  + chb + 32] = rr2.y;
      b[base + 130 + chb + 32] = rr2.z; b[base + 195 + chb + 32] = rr2.w;
      b[base       + chb + 48] = rr3.x; b[base + 65  + chb + 48] = rr3.y;
      b[base + 130 + chb + 48] = rr3.z; b[base + 195 + chb + 48] = rr3.w;
    } else {
#pragma unroll
      for (int i = 0; i < 16; ++i) {
        int idx = tid + 256 * i;
        int tl = idx & 63, ch = idx >> 6;
        b[tl * 65 + ch] = rs[i];
      }
    }
  };

  // prologue: subtiles 0 and 1
  issue(0); commit(0);
  issue(1); commit(1);

  float z0 = 0, z1 = 0, z2 = 0, z3 = 0, z4 = 0, z5 = 0, z6 = 0, z7 = 0;
  float4 oq = make_float4(0.f, 0.f, 0.f, 0.f);

  for (int k = 0; k < nsub; ++k) {
    __syncthreads();
    if (k == 0 && tid < 64) {
      float x0 = lds[0][lane];             // x_ext(e0)
      z0 = cf.zi0 * x0; z1 = cf.zi1 * x0; z2 = cf.zi2 * x0; z3 = cf.zi3 * x0;
      z4 = cf.zi4 * x0; z5 = cf.zi5 * x0; z6 = cf.zi6 * x0; z7 = cf.zi7 * x0;
    }
    if (k + 2 < nsub) issue(k + 2);
    if (tid < 64) {
      const float* tile = lds[k % 3];
#pragma unroll
      for (int tl = 0; tl < 64; ++tl) {
        float xin = tile[tl * 65 + lane];
        float yv; IIR_STEP(xin, yv);
        if (QOFF == 1) {                   // c==0 scalar head e=0,1,2 (grp1 q1..3)
          if (k == 0 && tl < 3) yb[2048 + mIdx * 4 + tl + 1] = yv;
        }
        const int q = (tl + QOFF) & 3;     // q = (e+1)&3, static after unroll
        if (q == 0) oq.x = yv;
        else if (q == 1) oq.y = yv;
        else if (q == 2) oq.z = yv;
        else {
          oq.w = yv;
          const int step = 64 * k + tl;
          if (step >= store_lo && step <= store_hi)
            yq[(size_t)((e0 + step + 5) >> 2) * 512 + mIdx] = oq;
        }
      }
    }
    if (k + 2 < nsub) commit(k + 2);
  }
}

__global__ __launch_bounds__(256) void k_fwd2(const float* __restrict__ x,
                                              float* __restrict__ yb, Coefs cf) {
  __shared__ float lds[3][4160];           // 49.9 KB -> 3 blocks/CU
  const int c  = blockIdx.x;               // chunk 0..128
  const int m0 = blockIdx.y * 64;          // channel tile
  if (c == 0)
    run_chunk<1, false>(x, yb, cf, lds, m0, 0, 8, 6, 510);
  else if (c == 128)
    run_chunk<0, false>(x, yb, cf, lds, m0, 65283, 5, 255, 307);
  else
    run_chunk<0, true>(x, yb, cf, lds, m0, 512 * c - 253, 12, 255, 763);
}

// ---------------- K2: backward chunked scan y -> quad-packed decimated output
// (unchanged from round 3; reads yb at 1KB granule, writes ot2 1KB granule)
__global__ __launch_bounds__(256) void k_bwd(const float* __restrict__ yb,
                                             float* __restrict__ ot2, Coefs cf) {
  const int m = blockIdx.y * 256 + threadIdx.x;
  const int c = blockIdx.x;
  const int own_lo = 256 * c;
  float z0, z1, z2, z3, z4, z5, z6, z7;
  int g_begin;
  if (c <= 1) {
    float y0 = yb[(size_t)16398 * 2048 + (size_t)m * 4 + 2];   // s=65594 (u=0)
    z0 = cf.zi0 * y0; z1 = cf.zi1 * y0; z2 = cf.zi2 * y0; z3 = cf.zi3 * y0;
    z4 = cf.zi4 * y0; z5 = cf.zi5 * y0; z6 = cf.zi6 * y0; z7 = cf.zi7 * y0;
#pragma unroll
    for (int s = 65594; s >= 65584; --s) {       // u = 0..10 (no valid outputs)
      float yin = yb[(size_t)(s >> 2) * 2048 + (size_t)m * 4 + (s & 3)];
      float wv; IIR_STEP(yin, wv);
      (void)wv;
    }
    g_begin = 16395;
  } else {
    g_begin = 16463 - 64 * c;                    // u=256c-261 at q3 of g_begin
    float y0 = yb[(size_t)g_begin * 2048 + (size_t)m * 4 + 3];
    z0 = cf.zi0 * y0; z1 = cf.zi1 * y0; z2 = cf.zi2 * y0; z3 = cf.zi3 * y0;
    z4 = cf.zi4 * y0; z5 = cf.zi5 * y0; z6 = cf.zi6 * y0; z7 = cf.zi7 * y0;
  }
  const int g_stop = max(1, 16334 - 64 * c);
  const float4* yv = reinterpret_cast<const float4*>(yb);
  auto ld = [&](int r) {
    int rr = r < 0 ? 0 : r;
    return yv[(size_t)rr * 512 + m];
  };
  float4 b0 = ld(g_begin), b1 = ld(g_begin - 1), b2 = ld(g_begin - 2), b3 = ld(g_begin - 3);
  float4 b4 = ld(g_begin - 4), b5 = ld(g_begin - 5), b6 = ld(g_begin - 6), b7 = ld(g_begin - 7);
  for (int g = g_begin; g >= g_stop; g -= 4) {
    float4 c0 = b0, c1 = b1, c2 = b2, c3 = b3;
    b0 = b4; b1 = b5; b2 = b6; b3 = b7;
    b4 = ld(g - 8); b5 = ld(g - 9); b6 = ld(g - 10); b7 = ld(g - 11);
    float4 pack;
#pragma unroll
    for (int j = 0; j < 4; ++j) {
      float4 q = (j == 0) ? c0 : (j == 1) ? c1 : (j == 2) ? c2 : c3;
      float w3, w2, w1, w0;
      IIR_STEP(q.w, w3);   // ascending u within group: q3,q2,q1,q0
      IIR_STEP(q.z, w2);
      IIR_STEP(q.y, w1);
      IIR_STEP(q.x, w0);
      (void)w3; (void)w2; (void)w1;
      if (j == 0) pack.w = w0;          // n = g-8
      else if (j == 1) pack.z = w0;     // n = g-9
      else if (j == 2) pack.y = w0;     // n = g-10
      else pack.x = w0;                 // n = g-11
    }
    if (65594 - 4 * g >= own_lo && g >= 11 && g <= 16391)
      *reinterpret_cast<float4*>(ot2 + (size_t)((g - 11) >> 2) * 2048 + (size_t)m * 4) = pack;
  }
}

// ---------------- K3: quad-packed ot2[qn][m][4] -> out[m][16384] --------------
__global__ __launch_bounds__(256) void k_outT(const float* __restrict__ ot2,
                                              float* __restrict__ out) {
  __shared__ float4 lds4[64 * 65];      // pitch 65 float4s: bank-perfect
  const int q0 = blockIdx.x * 64;       // quad tile (4096 quads total)
  const int m0 = blockIdx.y * 64;
  const int tid = threadIdx.x;
#pragma unroll
  for (int i = 0; i < 16; ++i) {
    int idx = tid + i * 256;
    int ql = idx >> 6;                  // wave-uniform
    int ml = idx & 63;                  // lane -> 1KB contiguous read
    lds4[ql * 65 + ml] = *reinterpret_cast<const float4*>(
        ot2 + (size_t)(q0 + ql) * 2048 + (size_t)(m0 + ml) * 4);
  }
  __syncthreads();
#pragma unroll
  for (int i = 0; i < 16; ++i) {
    int idx = tid + i * 256;
    int ml = idx >> 6;                  // wave-uniform
    int ql = idx & 63;                  // lane -> 1KB contiguous write
    float4 v = lds4[ql * 65 + ml];
    *reinterpret_cast<float4*>(
        out + (size_t)(m0 + ml) * 16384 + (size_t)(q0 + ql) * 4) = v;
  }
}

// ---------------- host: exact cheby1/zi design in double ----------------------
static void solve8(double Mm[8][9], double* zi) {
  for (int col = 0; col < 8; ++col) {
    int piv = col;
    for (int r = col + 1; r < 8; ++r)
      if (std::fabs(Mm[r][col]) > std::fabs(Mm[piv][col])) piv = r;
    if (piv != col)
      for (int j = 0; j < 9; ++j) { double t = Mm[col][j]; Mm[col][j] = Mm[piv][j]; Mm[piv][j] = t; }
    double d = Mm[col][col];
    for (int j = col; j < 9; ++j) Mm[col][j] /= d;
    for (int r = 0; r < 8; ++r)
      if (r != col) {
        double f = Mm[r][col];
        if (f != 0.0)
          for (int j = col; j < 9; ++j) Mm[r][j] -= f * Mm[col][j];
      }
  }
  for (int i = 0; i < 8; ++i) zi[i] = Mm[i][8];
}

static Coefs make_coefs() {
  using cd = std::complex<double>;
  const int N = 8;
  const double rp = 0.05, Wn = 0.8 / 4.0;
  double eps = std::sqrt(std::pow(10.0, 0.1 * rp) - 1.0);
  double mu = std::asinh(1.0 / eps) / N;
  cd p[8];
  for (int i = 0; i < N; ++i) {
    double th = M_PI * (2.0 * (i + 1) - 1.0) / (2.0 * N);
    p[i] = cd(-std::sinh(mu) * std::sin(th), std::cosh(mu) * std::cos(th));
  }
  cd pr(1.0, 0.0);
  for (int i = 0; i < N; ++i) pr *= -p[i];
  double g = pr.real();
  g /= std::sqrt(1.0 + eps * eps);                 // N even
  const double fs = 2.0;
  double warped = 2.0 * fs * std::tan(M_PI * Wn / fs);
  for (int i = 0; i < N; ++i) p[i] *= warped;
  g *= std::pow(warped, (double)N);
  const double fs2 = 2.0 * fs;
  cd pd[8], dpr(1.0, 0.0);
  for (int i = 0; i < N; ++i) {
    pd[i] = (cd(fs2, 0.0) + p[i]) / (cd(fs2, 0.0) - p[i]);
    dpr *= (cd(fs2, 0.0) - p[i]);
  }
  double gd = g * (cd(1.0, 0.0) / dpr).real();
  static const double binom[9] = {1, 8, 28, 56, 70, 56, 28, 8, 1};
  double b[9], a[9];
  for (int i = 0; i < 9; ++i) b[i] = gd * binom[i];
  cd cp[9]; cp[0] = cd(1, 0);
  for (int i = 1; i < 9; ++i) cp[i] = cd(0, 0);
  for (int i = 0; i < N; ++i)
    for (int j = i + 1; j >= 1; --j) cp[j] -= pd[i] * cp[j - 1];
  for (int i = 0; i < 9; ++i) a[i] = cp[i].real();
  double Mm[8][9];
  for (int i = 0; i < 8; ++i) {
    for (int j = 0; j < 9; ++j) Mm[i][j] = 0.0;
    Mm[i][0] += a[i + 1];
    Mm[i][i] += 1.0;
    if (i < 7) Mm[i][i + 1] = -1.0;
    Mm[i][8] = b[i + 1] - a[i + 1] * b[0];
  }
  double zi[8];
  solve8(Mm, zi);
  Coefs cf;
  cf.b0 = (float)b[0]; cf.b1 = (float)b[1]; cf.b2 = (float)b[2]; cf.b3 = (float)b[3];
  cf.b4 = (float)b[4]; cf.b5 = (float)b[5]; cf.b6 = (float)b[6]; cf.b7 = (float)b[7];
  cf.b8 = (float)b[8];
  cf.na1 = (float)(-a[1]); cf.na2 = (float)(-a[2]); cf.na3 = (float)(-a[3]);
  cf.na4 = (float)(-a[4]); cf.na5 = (float)(-a[5]); cf.na6 = (float)(-a[6]);
  cf.na7 = (float)(-a[7]); cf.na8 = (float)(-a[8]);
  cf.zi0 = (float)zi[0]; cf.zi1 = (float)zi[1]; cf.zi2 = (float)zi[2]; cf.zi3 = (float)zi[3];
  cf.zi4 = (float)zi[4]; cf.zi5 = (float)zi[5]; cf.zi6 = (float)zi[6]; cf.zi7 = (float)zi[7];
  return cf;
}

}  // namespace

extern "C" void kernel_launch(void* const* d_in, const int* in_sizes, int n_in,
                              void* d_out, int out_size, void* d_ws, size_t ws_size,
                              hipStream_t stream) {
  (void)in_sizes; (void)n_in; (void)out_size; (void)ws_size;
  const float* x = (const float*)d_in[0];
  float* out = (float*)d_out;
  float* yb  = (float*)d_ws;                       // 134.4 MB
  float* ot2 = yb + YB_ROWS * 2048;                // 33.6 MB
  Coefs cf = make_coefs();                         // pure host math, capture-safe
  hipLaunchKernelGGL(k_fwd2, dim3(129, NCH / 64), dim3(256), 0, stream, x, yb, cf);
  hipLaunchKernelGGL(k_bwd, dim3(257, 2), dim3(256), 0, stream, yb, ot2, cf);
  hipLaunchKernelGGL(k_outT, dim3(4096 / 64, NCH / 64), dim3(256), 0, stream, ot2, out);
}